// Round 8
// baseline (562.947 us; speedup 1.0000x reference)
//
#include <hip/hip_runtime.h>

#define G 3
#define K 40
#define S 1024
#define NB 32
#define CH 30
#define T 16384
#define TP 4096
#define M 131072           // NB*TP
#define CT (CH*T)          // 491520
#define OUT_Q (NB*CH*T)    // 15728640
#define MARGIN 4e-3f

typedef __attribute__((ext_vector_type(8))) short short8;
typedef __attribute__((ext_vector_type(4))) float f32x4;

// ---- workspace layout ----
#define WS_LOSS 0
#define WS_E2   64                        // float[3][1024] = 12288
#define WS_AH0  12352                     // short8[3*64*64] = 196608 each
#define WS_AL0  208960
#define WS_AH1  405568
#define WS_AL1  602176

static __device__ __forceinline__ unsigned short f2bf(float f) {
    union { float f; unsigned int u; } v; v.f = f;
    unsigned int u = v.u;
    return (unsigned short)((u + 0x7fffu + ((u >> 16) & 1u)) >> 16);   // RNE
}
static __device__ __forceinline__ float bf2f(unsigned short h) {
    union { unsigned int u; float f; } v; v.u = ((unsigned int)h) << 16;
    return v.f;
}
static __device__ __forceinline__ void split_bf(float f, short8& h, short8& l, int j) {
    unsigned short hh = f2bf(f);
    float r = f - bf2f(hh);
    unsigned short ll = f2bf(r);
    h[j] = (short)hh; l[j] = (short)ll;
}

// ================= prep: fragments + e2 + loss zero (proven rounds 5-7) =================
__global__ void vq_prep_frag(const float* __restrict__ cb, short8* __restrict__ AH0,
                             short8* __restrict__ AL0, short8* __restrict__ AH1,
                             short8* __restrict__ AL1, float* __restrict__ e2,
                             double* __restrict__ loss) {
    int t = blockIdx.x * 256 + threadIdx.x;      // [0, 3*64*64)
    if (t == 0) *loss = 0.0;
    if (t >= G * 64 * 64) return;
    const int lane = t & 63;
    const int st   = (t >> 6) & 63;
    const int g    = t >> 12;
    const int lmod = lane & 15, lgrp = lane >> 4;
    const int s0   = st * 16;
    const float* cbg = cb + (size_t)g * S * K;

    if (lane < 16) {
        const float* row = cbg + (size_t)(s0 + lane) * K;
        float acc = 0.f;
        #pragma unroll
        for (int k = 0; k < K; ++k) acc = fmaf(row[k], row[k], acc);
        e2[g * S + s0 + lane] = -0.5f * acc;     // maximize D = x.e - 0.5||e||^2
    }

    const float* crow = cbg + (size_t)(s0 + lmod) * K;
    float4 c0 = *(const float4*)(crow + lgrp * 8);
    float4 c1 = *(const float4*)(crow + lgrp * 8 + 4);
    float4 t0 = make_float4(0.f, 0.f, 0.f, 0.f), t1 = t0;
    if (lgrp == 0) {
        t0 = *(const float4*)(crow + 32);
        t1 = *(const float4*)(crow + 36);
    }
    short8 ah0, al0, ah1, al1;
    split_bf(c0.x, ah0, al0, 0); split_bf(c0.y, ah0, al0, 1);
    split_bf(c0.z, ah0, al0, 2); split_bf(c0.w, ah0, al0, 3);
    split_bf(c1.x, ah0, al0, 4); split_bf(c1.y, ah0, al0, 5);
    split_bf(c1.z, ah0, al0, 6); split_bf(c1.w, ah0, al0, 7);
    split_bf(t0.x, ah1, al1, 0); split_bf(t0.y, ah1, al1, 1);
    split_bf(t0.z, ah1, al1, 2); split_bf(t0.w, ah1, al1, 3);
    split_bf(t1.x, ah1, al1, 4); split_bf(t1.y, ah1, al1, 5);
    split_bf(t1.z, ah1, al1, 6); split_bf(t1.w, ah1, al1, 7);

    const int slot = (g * 64 + st) * 64 + lane;
    AH0[slot] = ah0; AL0[slot] = al0; AH1[slot] = ah1; AL1[slot] = al1;
}

// ======== main: LDS-staged fragments, 8 m-tiles/wave, 2 s-tiles per barrier ========
__global__ __launch_bounds__(256, 2) void vq_main_lds(
        const float* __restrict__ z, const float* __restrict__ cb,
        const short8* __restrict__ AH0, const short8* __restrict__ AL0,
        const short8* __restrict__ AH1, const short8* __restrict__ AL1,
        const float* __restrict__ e2, float* __restrict__ out,
        double* __restrict__ loss) {
    __shared__ short8 frag[2][2][4][64];        // [buf][sub][array][lane] = 16 KB
    __shared__ float  sV1[4][128], sV2[4][128];
    __shared__ int    sIdx[4][128];
    __shared__ float  sXq[4][K];
    __shared__ double red[256];

    const int lane = threadIdx.x & 63;
    const int w    = threadIdx.x >> 6;
    const int g    = blockIdx.x >> 8;                       // 256 blocks per group
    const int qbase = ((blockIdx.x & 255) << 9) + (w << 7); // 128 queries per wave
    const int n    = qbase >> 12;
    const int tp0  = qbase & 4095;
    const int lmod = lane & 15, lgrp = lane >> 4;

    const float* zg  = z + (size_t)n * CT + (size_t)g * K * TP;
    const float* cbg = cb + (size_t)g * S * K;
    const float* e2g = e2 + g * S;

    // wave w stages fragment-array w for the whole block
    const short8* src = (w == 0) ? AH0 : (w == 1) ? AL0 : (w == 2) ? AH1 : AL1;
    src += (size_t)g * 64 * 64;                 // + st*64 + lane per tile

    // ---- x fragments: 8 m-tiles of 16 queries (round-4/5/7 verified layout) ----
    short8 xh0[8], xl0[8], xh1[8], xl1[8];
    #pragma unroll
    for (int mt = 0; mt < 8; ++mt) {
        int tp = tp0 + mt * 16 + lmod;
        #pragma unroll
        for (int j = 0; j < 8; ++j) {
            split_bf(zg[(size_t)(lgrp * 8 + j) * TP + tp], xh0[mt], xl0[mt], j);
            float f1 = (lgrp == 0) ? zg[(size_t)(32 + j) * TP + tp] : 0.f;
            split_bf(f1, xh1[mt], xl1[mt], j);
        }
    }

    float v1[8], v2[8]; int i1[8];
    #pragma unroll
    for (int mt = 0; mt < 8; ++mt) { v1[mt] = -3.4e38f; v2[mt] = -3.4e38f; i1[mt] = 0; }

    // ---- prologue: stage s-tiles 0,1 into buf 0 ----
    frag[0][0][w][lane] = src[lane];
    frag[0][1][w][lane] = src[64 + lane];
    __syncthreads();

    // ---- main loop: 32 iterations x 2 s-tiles, one barrier per iteration ----
    #pragma unroll 1
    for (int it = 0; it < 32; ++it) {
        const int cbuf = it & 1, nbuf = cbuf ^ 1;
        short8 nxtA, nxtB;
        if (it < 31) {
            nxtA = src[(2 * it + 2) * 64 + lane];           // issue early (VMEM)
            nxtB = src[(2 * it + 3) * 64 + lane];
        }

        #pragma unroll
        for (int sub = 0; sub < 2; ++sub) {
            const int st = 2 * it + sub;
            short8 ah0 = frag[cbuf][sub][0][lane];
            short8 al0 = frag[cbuf][sub][1][lane];
            short8 ah1 = frag[cbuf][sub][2][lane];
            short8 al1 = frag[cbuf][sub][3][lane];
            f32x4 e2v = *(const f32x4*)(e2g + st * 16 + lgrp * 4);
            const int sbase = st * 16 + lgrp * 4;

            #pragma unroll
            for (int mt = 0; mt < 8; ++mt) {
                f32x4 d = __builtin_amdgcn_mfma_f32_16x16x32_bf16(ah0, xh0[mt], e2v, 0, 0, 0);
                d = __builtin_amdgcn_mfma_f32_16x16x32_bf16(al0, xh0[mt], d, 0, 0, 0);
                d = __builtin_amdgcn_mfma_f32_16x16x32_bf16(ah0, xl0[mt], d, 0, 0, 0);
                d = __builtin_amdgcn_mfma_f32_16x16x32_bf16(ah1, xh1[mt], d, 0, 0, 0);
                d = __builtin_amdgcn_mfma_f32_16x16x32_bf16(al1, xh1[mt], d, 0, 0, 0);
                d = __builtin_amdgcn_mfma_f32_16x16x32_bf16(ah1, xl1[mt], d, 0, 0, 0);
                #pragma unroll
                for (int j = 0; j < 4; ++j) {
                    float sj = d[j];
                    v2[mt] = __builtin_amdgcn_fmed3f(v1[mt], v2[mt], sj);  // 2nd-largest
                    bool cc = sj > v1[mt];
                    v1[mt] = fmaxf(v1[mt], sj);
                    i1[mt] = cc ? (sbase + j) : i1[mt];
                }
            }
        }

        if (it < 31) {
            frag[nbuf][0][w][lane] = nxtA;       // write-late (vmcnt drains here)
            frag[nbuf][1][w][lane] = nxtB;
        }
        __syncthreads();
    }

    // ---- cross-lane merge (lanes m, m+16, m+32, m+48 share a query column) ----
    #pragma unroll
    for (int mt = 0; mt < 8; ++mt) {
        float a1 = v1[mt], a2 = v2[mt];
        int ii = i1[mt];
        #pragma unroll
        for (int off = 16; off < 64; off <<= 1) {
            float p1 = __shfl_xor(a1, off);
            float p2 = __shfl_xor(a2, off);
            int   pi = __shfl_xor(ii, off);
            float lo = fminf(a1, p1);
            a2 = fmaxf(fmaxf(a2, p2), lo);
            bool take = (p1 > a1) || (p1 == a1 && pi < ii);
            ii = take ? pi : ii;
            a1 = fmaxf(a1, p1);
        }
        if (lane < 16) {
            sV1[w][mt * 16 + lane] = a1;
            sV2[w][mt * 16 + lane] = a2;
            sIdx[w][mt * 16 + lane] = ii;
        }
    }
    __syncthreads();

    // ---- rare exact fp64 full rescan for near-tie queries (wave-cooperative) ----
    for (int rep = 0; rep < 2; ++rep) {
        int q = rep * 64 + lane;
        bool need = (sV1[w][q] - sV2[w][q]) < MARGIN;
        unsigned long long mask = __ballot(need);
        while (mask) {
            int src_l = __ffsll((unsigned long long)mask) - 1; mask &= mask - 1;
            int qq = rep * 64 + src_l;
            int tpq = tp0 + qq;
            __threadfence_block();
            if (lane < K) sXq[w][lane] = zg[(size_t)lane * TP + tpq];
            __threadfence_block();
            double bestv = 1e300; int besti = 0;
            #pragma unroll 1
            for (int si = 0; si < 16; ++si) {
                int s = lane * 16 + si;
                const float* cr = cbg + (size_t)s * K;
                double acc = 0.0, en = 0.0;
                #pragma unroll 1
                for (int k = 0; k < K; ++k) {
                    double ev = (double)cr[k];
                    acc = fma(ev, (double)sXq[w][k], acc);
                    en  = fma(ev, ev, en);
                }
                double sc = 0.5 * en - acc;
                if (sc < bestv) { bestv = sc; besti = s; }
            }
            #pragma unroll
            for (int off = 1; off < 64; off <<= 1) {
                double pv = __shfl_xor(bestv, off);
                int    pi = __shfl_xor(besti, off);
                if (pv < bestv || (pv == bestv && pi < besti)) { bestv = pv; besti = pi; }
            }
            if (lane == 0) sIdx[w][qq] = besti;
        }
    }
    __syncthreads();

    // ---- gather winners -> output (coalesced), fp64 loss partials (group 2) ----
    double lsum = 0.0;
    #pragma unroll 1
    for (int rep = 0; rep < 2; ++rep) {
        int q = rep * 64 + lane;
        int tpq = tp0 + q;
        int idx = sIdx[w][q];
        const float* cr = cbg + (size_t)idx * K;
        float* op = out + (size_t)n * CT + (size_t)g * K * TP + tpq;
        #pragma unroll
        for (int k = 0; k < K; ++k) {
            float qv = cr[k];
            op[(size_t)k * TP] = qv;
            if (g == 2) {
                float xv = zg[(size_t)k * TP + tpq];
                double dd = (double)qv - (double)xv;
                lsum = fma(dd, dd, lsum);
            }
        }
    }

    if (g == 2) {
        red[threadIdx.x] = lsum;
        __syncthreads();
        for (int off = 128; off > 0; off >>= 1) {
            if (threadIdx.x < off) red[threadIdx.x] += red[threadIdx.x + off];
            __syncthreads();
        }
        if (threadIdx.x == 0) atomicAdd(loss, red[0]);
    }
}

// ---------------- finalize: scalar loss ----------------
__global__ void vq_fin_kernel(const double* __restrict__ loss, float* __restrict__ out) {
    out[OUT_Q] = (float)(0.25 * (*loss) / (double)((long long)M * K));
}

extern "C" void kernel_launch(void* const* d_in, const int* in_sizes, int n_in,
                              void* d_out, int out_size, void* d_ws, size_t ws_size,
                              hipStream_t stream) {
    const float* z  = (const float*)d_in[0];
    const float* cb = (const float*)d_in[1];
    float* out = (float*)d_out;

    char* ws = (char*)d_ws;
    double* loss = (double*)(ws + WS_LOSS);
    float*  e2   = (float*)(ws + WS_E2);
    short8* AH0 = (short8*)(ws + WS_AH0);
    short8* AL0 = (short8*)(ws + WS_AL0);
    short8* AH1 = (short8*)(ws + WS_AH1);
    short8* AL1 = (short8*)(ws + WS_AL1);

    vq_prep_frag<<<dim3(48), dim3(256), 0, stream>>>(cb, AH0, AL0, AH1, AL1, e2, loss);
    vq_main_lds<<<dim3(768), dim3(256), 0, stream>>>(z, cb, AH0, AL0, AH1, AL1, e2, out, loss);
    vq_fin_kernel<<<dim3(1), dim3(1), 0, stream>>>(loss, out);
}

// Round 9
// 348.778 us; speedup vs baseline: 1.6141x; 1.6141x over previous
//
#include <hip/hip_runtime.h>

#define G 3
#define K 40
#define S 1024
#define NB 32
#define CH 30
#define T 16384
#define TP 4096
#define M 131072           // NB*TP
#define CT (CH*T)          // 491520
#define OUT_Q (NB*CH*T)    // 15728640
#define MARGIN 4e-3f

typedef __attribute__((ext_vector_type(8))) short short8;
typedef __attribute__((ext_vector_type(4))) float f32x4;

// ---- workspace layout ----
#define WS_LOSS 0
#define WS_E2   64                        // float[3][1024] = 12288
#define WS_AH0  12352                     // short8[3*64*64] = 196608 each
#define WS_AL0  208960
#define WS_AH1  405568
#define WS_AL1  602176

static __device__ __forceinline__ unsigned short f2bf(float f) {
    union { float f; unsigned int u; } v; v.f = f;
    unsigned int u = v.u;
    return (unsigned short)((u + 0x7fffu + ((u >> 16) & 1u)) >> 16);   // RNE
}
static __device__ __forceinline__ float bf2f(unsigned short h) {
    union { unsigned int u; float f; } v; v.u = ((unsigned int)h) << 16;
    return v.f;
}
static __device__ __forceinline__ void split_bf(float f, short8& h, short8& l, int j) {
    unsigned short hh = f2bf(f);
    float r = f - bf2f(hh);
    unsigned short ll = f2bf(r);
    h[j] = (short)hh; l[j] = (short)ll;
}

// ================= prep: fragments + e2 + loss zero (proven rounds 5-8) =================
__global__ void vq_prep_frag(const float* __restrict__ cb, short8* __restrict__ AH0,
                             short8* __restrict__ AL0, short8* __restrict__ AH1,
                             short8* __restrict__ AL1, float* __restrict__ e2,
                             double* __restrict__ loss) {
    int t = blockIdx.x * 256 + threadIdx.x;      // [0, 3*64*64)
    if (t == 0) *loss = 0.0;
    if (t >= G * 64 * 64) return;
    const int lane = t & 63;
    const int st   = (t >> 6) & 63;
    const int g    = t >> 12;
    const int lmod = lane & 15, lgrp = lane >> 4;
    const int s0   = st * 16;
    const float* cbg = cb + (size_t)g * S * K;

    if (lane < 16) {
        const float* row = cbg + (size_t)(s0 + lane) * K;
        float acc = 0.f;
        #pragma unroll
        for (int k = 0; k < K; ++k) acc = fmaf(row[k], row[k], acc);
        e2[g * S + s0 + lane] = -0.5f * acc;     // maximize D = x.e - 0.5||e||^2
    }

    const float* crow = cbg + (size_t)(s0 + lmod) * K;
    float4 c0 = *(const float4*)(crow + lgrp * 8);
    float4 c1 = *(const float4*)(crow + lgrp * 8 + 4);
    float4 t0 = make_float4(0.f, 0.f, 0.f, 0.f), t1 = t0;
    if (lgrp == 0) {
        t0 = *(const float4*)(crow + 32);
        t1 = *(const float4*)(crow + 36);
    }
    short8 ah0, al0, ah1, al1;
    split_bf(c0.x, ah0, al0, 0); split_bf(c0.y, ah0, al0, 1);
    split_bf(c0.z, ah0, al0, 2); split_bf(c0.w, ah0, al0, 3);
    split_bf(c1.x, ah0, al0, 4); split_bf(c1.y, ah0, al0, 5);
    split_bf(c1.z, ah0, al0, 6); split_bf(c1.w, ah0, al0, 7);
    split_bf(t0.x, ah1, al1, 0); split_bf(t0.y, ah1, al1, 1);
    split_bf(t0.z, ah1, al1, 2); split_bf(t0.w, ah1, al1, 3);
    split_bf(t1.x, ah1, al1, 4); split_bf(t1.y, ah1, al1, 5);
    split_bf(t1.z, ah1, al1, 6); split_bf(t1.w, ah1, al1, 7);

    const int slot = (g * 64 + st) * 64 + lane;
    AH0[slot] = ah0; AL0[slot] = al0; AH1[slot] = ah1; AL1[slot] = al1;
}

// ==== main: LDS-staged fragments, 4 waves x 64 queries, 2 s-tiles per barrier ====
__global__ __launch_bounds__(256, 2) void vq_main_lds(
        const float* __restrict__ z, const float* __restrict__ cb,
        const short8* __restrict__ AH0, const short8* __restrict__ AL0,
        const short8* __restrict__ AH1, const short8* __restrict__ AL1,
        const float* __restrict__ e2, float* __restrict__ out,
        double* __restrict__ loss) {
    __shared__ short8 frag[2][2][4][64];        // [buf][sub][array][lane] = 16 KB
    __shared__ float  sV1[4][64], sV2[4][64];
    __shared__ int    sIdx[4][64];
    __shared__ float  sXq[4][K];
    __shared__ double red[256];

    const int lane = threadIdx.x & 63;
    const int w    = threadIdx.x >> 6;
    const int g    = blockIdx.x >> 9;                     // 512 blocks per group
    const int qbase = ((blockIdx.x & 511) << 8) + (w << 6); // 64 queries per wave
    const int n    = qbase >> 12;
    const int tp0  = qbase & 4095;
    const int lmod = lane & 15, lgrp = lane >> 4;

    const float* zg  = z + (size_t)n * CT + (size_t)g * K * TP;
    const float* cbg = cb + (size_t)g * S * K;
    const float* e2g = e2 + g * S;

    // wave w stages fragment-array w for the whole block
    const short8* src = (w == 0) ? AH0 : (w == 1) ? AL0 : (w == 2) ? AH1 : AL1;
    src += (size_t)g * 64 * 64;                 // + st*64 + lane per tile

    // ---- x fragments: 4 m-tiles of 16 queries (round-4/5/7 verified layout) ----
    short8 xh0[4], xl0[4], xh1[4], xl1[4];
    #pragma unroll
    for (int mt = 0; mt < 4; ++mt) {
        int tp = tp0 + mt * 16 + lmod;
        #pragma unroll
        for (int j = 0; j < 8; ++j) {
            split_bf(zg[(size_t)(lgrp * 8 + j) * TP + tp], xh0[mt], xl0[mt], j);
            float f1 = (lgrp == 0) ? zg[(size_t)(32 + j) * TP + tp] : 0.f;
            split_bf(f1, xh1[mt], xl1[mt], j);
        }
    }

    float v1[4], v2[4]; int i1[4];
    #pragma unroll
    for (int mt = 0; mt < 4; ++mt) { v1[mt] = -3.4e38f; v2[mt] = -3.4e38f; i1[mt] = 0; }

    // ---- prologue: stage s-tiles 0,1 into buf 0 ----
    frag[0][0][w][lane] = src[lane];
    frag[0][1][w][lane] = src[64 + lane];
    __syncthreads();

    // ---- main loop: 32 iterations x 2 s-tiles, one barrier per iteration ----
    #pragma unroll 1
    for (int it = 0; it < 32; ++it) {
        const int cbuf = it & 1, nbuf = cbuf ^ 1;
        short8 nxtA, nxtB;
        if (it < 31) {
            nxtA = src[(2 * it + 2) * 64 + lane];           // issue early (VMEM)
            nxtB = src[(2 * it + 3) * 64 + lane];
        }

        #pragma unroll
        for (int sub = 0; sub < 2; ++sub) {
            const int st = 2 * it + sub;
            short8 ah0 = frag[cbuf][sub][0][lane];
            short8 al0 = frag[cbuf][sub][1][lane];
            short8 ah1 = frag[cbuf][sub][2][lane];
            short8 al1 = frag[cbuf][sub][3][lane];
            f32x4 e2v = *(const f32x4*)(e2g + st * 16 + lgrp * 4);
            const int sbase = st * 16 + lgrp * 4;

            #pragma unroll
            for (int mt = 0; mt < 4; ++mt) {
                f32x4 d = __builtin_amdgcn_mfma_f32_16x16x32_bf16(ah0, xh0[mt], e2v, 0, 0, 0);
                d = __builtin_amdgcn_mfma_f32_16x16x32_bf16(al0, xh0[mt], d, 0, 0, 0);
                d = __builtin_amdgcn_mfma_f32_16x16x32_bf16(ah0, xl0[mt], d, 0, 0, 0);
                d = __builtin_amdgcn_mfma_f32_16x16x32_bf16(ah1, xh1[mt], d, 0, 0, 0);
                d = __builtin_amdgcn_mfma_f32_16x16x32_bf16(al1, xh1[mt], d, 0, 0, 0);
                d = __builtin_amdgcn_mfma_f32_16x16x32_bf16(ah1, xl1[mt], d, 0, 0, 0);
                #pragma unroll
                for (int j = 0; j < 4; ++j) {
                    float sj = d[j];
                    v2[mt] = __builtin_amdgcn_fmed3f(v1[mt], v2[mt], sj);  // 2nd-largest
                    bool cc = sj > v1[mt];
                    v1[mt] = fmaxf(v1[mt], sj);
                    i1[mt] = cc ? (sbase + j) : i1[mt];
                }
            }
        }

        if (it < 31) {
            frag[nbuf][0][w][lane] = nxtA;       // write-late (vmcnt drains here)
            frag[nbuf][1][w][lane] = nxtB;
        }
        __syncthreads();
    }

    // ---- cross-lane merge (lanes m, m+16, m+32, m+48 share a query column) ----
    #pragma unroll
    for (int mt = 0; mt < 4; ++mt) {
        float a1 = v1[mt], a2 = v2[mt];
        int ii = i1[mt];
        #pragma unroll
        for (int off = 16; off < 64; off <<= 1) {
            float p1 = __shfl_xor(a1, off);
            float p2 = __shfl_xor(a2, off);
            int   pi = __shfl_xor(ii, off);
            float lo = fminf(a1, p1);
            a2 = fmaxf(fmaxf(a2, p2), lo);
            bool take = (p1 > a1) || (p1 == a1 && pi < ii);
            ii = take ? pi : ii;
            a1 = fmaxf(a1, p1);
        }
        if (lane < 16) {
            sV1[w][mt * 16 + lane] = a1;
            sV2[w][mt * 16 + lane] = a2;
            sIdx[w][mt * 16 + lane] = ii;
        }
    }
    __syncthreads();

    // ---- rare exact fp64 full rescan for near-tie queries (wave-cooperative) ----
    {
        bool need = (sV1[w][lane] - sV2[w][lane]) < MARGIN;
        unsigned long long mask = __ballot(need);
        while (mask) {
            int qq = __ffsll((unsigned long long)mask) - 1; mask &= mask - 1;
            int tpq = tp0 + qq;
            __threadfence_block();
            if (lane < K) sXq[w][lane] = zg[(size_t)lane * TP + tpq];
            __threadfence_block();
            double bestv = 1e300; int besti = 0;
            #pragma unroll 1
            for (int si = 0; si < 16; ++si) {
                int s = lane * 16 + si;
                const float* cr = cbg + (size_t)s * K;
                double acc = 0.0, en = 0.0;
                #pragma unroll 1
                for (int k = 0; k < K; ++k) {
                    double ev = (double)cr[k];
                    acc = fma(ev, (double)sXq[w][k], acc);
                    en  = fma(ev, ev, en);
                }
                double sc = 0.5 * en - acc;
                if (sc < bestv) { bestv = sc; besti = s; }
            }
            #pragma unroll
            for (int off = 1; off < 64; off <<= 1) {
                double pv = __shfl_xor(bestv, off);
                int    pi = __shfl_xor(besti, off);
                if (pv < bestv || (pv == bestv && pi < besti)) { bestv = pv; besti = pi; }
            }
            if (lane == 0) sIdx[w][qq] = besti;
        }
    }
    __syncthreads();

    // ---- gather winners -> output (coalesced), fp64 loss partials (group 2) ----
    double lsum = 0.0;
    {
        int tpq = tp0 + lane;
        int idx = sIdx[w][lane];
        const float* cr = cbg + (size_t)idx * K;
        float* op = out + (size_t)n * CT + (size_t)g * K * TP + tpq;
        #pragma unroll
        for (int k = 0; k < K; ++k) {
            float qv = cr[k];
            op[(size_t)k * TP] = qv;
            if (g == 2) {
                float xv = zg[(size_t)k * TP + tpq];
                double dd = (double)qv - (double)xv;
                lsum = fma(dd, dd, lsum);
            }
        }
    }

    if (g == 2) {
        red[threadIdx.x] = lsum;
        __syncthreads();
        for (int off = 128; off > 0; off >>= 1) {
            if (threadIdx.x < off) red[threadIdx.x] += red[threadIdx.x + off];
            __syncthreads();
        }
        if (threadIdx.x == 0) atomicAdd(loss, red[0]);
    }
}

// ---------------- finalize: scalar loss ----------------
__global__ void vq_fin_kernel(const double* __restrict__ loss, float* __restrict__ out) {
    out[OUT_Q] = (float)(0.25 * (*loss) / (double)((long long)M * K));
}

extern "C" void kernel_launch(void* const* d_in, const int* in_sizes, int n_in,
                              void* d_out, int out_size, void* d_ws, size_t ws_size,
                              hipStream_t stream) {
    const float* z  = (const float*)d_in[0];
    const float* cb = (const float*)d_in[1];
    float* out = (float*)d_out;

    char* ws = (char*)d_ws;
    double* loss = (double*)(ws + WS_LOSS);
    float*  e2   = (float*)(ws + WS_E2);
    short8* AH0 = (short8*)(ws + WS_AH0);
    short8* AL0 = (short8*)(ws + WS_AL0);
    short8* AH1 = (short8*)(ws + WS_AH1);
    short8* AL1 = (short8*)(ws + WS_AL1);

    vq_prep_frag<<<dim3(48), dim3(256), 0, stream>>>(cb, AH0, AL0, AH1, AL1, e2, loss);
    vq_main_lds<<<dim3(1536), dim3(256), 0, stream>>>(z, cb, AH0, AL0, AH1, AL1, e2, out, loss);
    vq_fin_kernel<<<dim3(1), dim3(1), 0, stream>>>(loss, out);
}